// Round 1
// baseline (216.743 us; speedup 1.0000x reference)
//
#include <hip/hip_runtime.h>

typedef __bf16 bf16;
typedef __bf16 bf16x8 __attribute__((ext_vector_type(8)));
typedef float  f32x4  __attribute__((ext_vector_type(4)));

constexpr int NCLUS  = 8;
constexpr int HDIM   = 256;
constexpr int DIN    = 36;
constexpr int SEGCAP = 16384;          // per-cluster index capacity (mean 8192, 70-sigma safe)
constexpr int TPC    = SEGCAP / 64;    // 256 tiles per cluster
constexpr int LSTR   = 264;            // LDS row stride in bf16 (256 + 8 pad -> 4-dword bank skew)

// ---------------- workspace layout (bytes) ----------------
// cursor : [0, 32)
// order  : [256, 256 + 8*16384*4)            = 512 KB
// pin    : 8 * 64*256  bf16                  = 256 KB   (K padded 36->64, zeros)
// pmid   : 8*3 * 256*256 bf16                = 3 MB
// woutw  : 8*3*256 f32                       = 24 KB
constexpr size_t OFF_ORDER = 256;
constexpr size_t OFF_PIN   = OFF_ORDER + (size_t)NCLUS * SEGCAP * 4;
constexpr size_t OFF_PMID  = OFF_PIN + (size_t)NCLUS * 64 * 256 * 2;
constexpr size_t OFF_WOUT  = OFF_PMID + (size_t)NCLUS * 3 * 256 * 256 * 2;

__global__ void zero_cursor(int* cursor) {
    if (threadIdx.x < NCLUS) cursor[threadIdx.x] = 0;
}

// Partition point indices by cluster: one LDS histogram + one global atomic per
// cluster per block; order within a cluster is arbitrary (irrelevant to results).
__global__ void scatter_kernel(const int* __restrict__ cid, int* __restrict__ cursor,
                               int* __restrict__ order) {
    __shared__ int lhist[NCLUS];
    __shared__ int lbase[NCLUS];
    const int tid = threadIdx.x;
    const int i = blockIdx.x * 256 + tid;
    if (tid < NCLUS) lhist[tid] = 0;
    __syncthreads();
    const int c = cid[i];
    const int my = atomicAdd(&lhist[c], 1);
    __syncthreads();
    if (tid < NCLUS) lbase[tid] = atomicAdd(&cursor[tid], lhist[tid]);
    __syncthreads();
    const int pos = lbase[c] + my;
    if (pos < SEGCAP) order[c * SEGCAP + pos] = i;
}

// Weight-norm every row (fp32), then store bf16 in MFMA B-fragment order:
// packed[(kstep*16 + ntile)*512 + lane*8 + j] = Wn[n][k],
//   lane = ((k&31)>>3)*16 + (n&15), j = k&7, kstep = k>>5, ntile = n>>4.
__global__ void prep_kernel(const float* __restrict__ V_in,  const float* __restrict__ g_in,
                            const float* __restrict__ V_mid, const float* __restrict__ g_mid,
                            const float* __restrict__ V_out, const float* __restrict__ g_out,
                            bf16* __restrict__ pin, bf16* __restrict__ pmid,
                            float* __restrict__ woutw) {
    __shared__ float red[256];
    const int tid = threadIdx.x;
    const int bid = blockIdx.x;

    if (bid < NCLUS * HDIM) {                       // input layer rows: [C,H,D]
        const int c = bid >> 8, n = bid & 255;
        const float* vrow = V_in + (size_t)bid * DIN;
        float p = 0.f;
        if (tid < DIN) { float v = vrow[tid]; p = v * v; }
        red[tid] = p; __syncthreads();
        for (int s = 128; s > 0; s >>= 1) { if (tid < s) red[tid] += red[tid + s]; __syncthreads(); }
        const float scale = g_in[bid] / sqrtf(red[0]);
        if (tid < 64) {
            const int k = tid;
            const float val = (k < DIN) ? vrow[k] * scale : 0.f;
            const int lane = (((k & 31) >> 3) << 4) | (n & 15);
            const int idx = ((k >> 5) * 16 + (n >> 4)) * 512 + lane * 8 + (k & 7);
            pin[(size_t)c * 16384 + idx] = (bf16)val;
        }
    } else if (bid < NCLUS * HDIM + NCLUS * 3 * HDIM) {   // mid rows: [C,3,H,H]
        const int b2 = bid - NCLUS * HDIM;
        const int cl = b2 >> 8, n = b2 & 255;             // cl = c*3 + l
        const float* vrow = V_mid + ((size_t)(cl * 256 + n)) * 256;
        const float v = vrow[tid];
        red[tid] = v * v; __syncthreads();
        for (int s = 128; s > 0; s >>= 1) { if (tid < s) red[tid] += red[tid + s]; __syncthreads(); }
        const float scale = g_mid[cl * 256 + n] / sqrtf(red[0]);
        const int k = tid;
        const int lane = (((k & 31) >> 3) << 4) | (n & 15);
        const int idx = ((k >> 5) * 16 + (n >> 4)) * 512 + lane * 8 + (k & 7);
        pmid[(size_t)cl * 65536 + idx] = (bf16)(vrow[k] * scale);
    } else {                                              // output rows: [C,3,H]
        const int cr = bid - (NCLUS * HDIM + NCLUS * 3 * HDIM);  // 0..23
        const float* vrow = V_out + (size_t)cr * 256;
        const float v = vrow[tid];
        red[tid] = v * v; __syncthreads();
        for (int s = 128; s > 0; s >>= 1) { if (tid < s) red[tid] += red[tid + s]; __syncthreads(); }
        const float scale = g_out[cr] / sqrtf(red[0]);
        woutw[cr * 256 + tid] = vrow[tid] * scale;
    }
}

// One layer, in place: Hout[64,256] = relu(Hin[64,K] @ Wn^T + b), K = 32*KSTEPS.
// Wave w owns all 64 rows x cols [64w,64w+64): 4x4 tiles of 16x16x32 bf16 MFMA.
// A-frag: A[m=lane&15][k=quad*8+j] (ds_read_b128, 2-way banks = free).
// B-frag: prepacked, lane-linear global_load_dwordx4 (L2-resident).
// D: D[m=quad*4+reg][n=lane&15]. Compute -> barrier -> in-place epilogue -> barrier.
template <int KSTEPS>
__device__ __forceinline__ void layer_fused(bf16* __restrict__ buf,
                                            const bf16* __restrict__ wp,
                                            const float* __restrict__ bias,
                                            int lane, int w) {
    const int quad = lane >> 4, l15 = lane & 15;
    f32x4 acc[4][4];
#pragma unroll
    for (int r = 0; r < 4; r++)
#pragma unroll
        for (int j = 0; j < 4; j++) acc[r][j] = (f32x4){0.f, 0.f, 0.f, 0.f};

#pragma unroll
    for (int ks = 0; ks < KSTEPS; ks++) {
        bf16x8 af[4];
#pragma unroll
        for (int r = 0; r < 4; r++)
            af[r] = *(const bf16x8*)(buf + (16 * r + l15) * LSTR + ks * 32 + quad * 8);
#pragma unroll
        for (int j = 0; j < 4; j++) {
            const bf16x8 bfr = *(const bf16x8*)(wp + (size_t)((ks * 16 + (4 * w + j)) * 512 + lane * 8));
#pragma unroll
            for (int r = 0; r < 4; r++)
                acc[r][j] = __builtin_amdgcn_mfma_f32_16x16x32_bf16(af[r], bfr, acc[r][j], 0, 0, 0);
        }
    }
    __syncthreads();   // everyone done reading buf
#pragma unroll
    for (int j = 0; j < 4; j++) {
        const int col = 64 * w + 16 * j + l15;
        const float bv = bias[col];
#pragma unroll
        for (int r = 0; r < 4; r++)
#pragma unroll
            for (int i = 0; i < 4; i++) {
                float v = acc[r][j][i] + bv;
                buf[(16 * r + quad * 4 + i) * LSTR + col] = (bf16)(v > 0.f ? v : 0.f);
            }
    }
    __syncthreads();   // buf ready for next layer
}

__global__ __launch_bounds__(256) void mlp_kernel(
    const float* __restrict__ X,
    const float* __restrict__ b_in, const float* __restrict__ b_mid,
    const float* __restrict__ b_out,
    const int* __restrict__ counts, const int* __restrict__ order,
    const bf16* __restrict__ pin, const bf16* __restrict__ pmid,
    const float* __restrict__ woutw, float* __restrict__ out) {
    const int c = blockIdx.x >> 8;          // TPC = 256 tiles per cluster
    const int tile = blockIdx.x & (TPC - 1);
    const int count = counts[c];
    const int s0 = tile * 64;
    if (s0 >= count) return;

    __shared__ __align__(16) bf16 buf[64 * LSTR];   // 33.8 KB, single in-place activation buffer
    __shared__ int sidx[64];
    __shared__ float sx[192];

    const int tid = threadIdx.x;
    const int lane = tid & 63;
    const int w = tid >> 6;

    if (tid < 64) {
        const int g = s0 + tid;
        sidx[tid] = order[c * SEGCAP + (g < count ? g : s0)];  // pad lanes replicate a valid point
    }
    __syncthreads();
    if (tid < 192) sx[tid] = X[(size_t)sidx[tid / 3] * 3 + tid % 3];
    __syncthreads();

    // Positional encoding -> bf16, cols 36..63 zero-padded (weights also zero there).
    for (int v = tid; v < 64 * 64; v += 256) {
        const int p = v >> 6, col = v & 63;
        float val = 0.f;
        if (col < DIN) {
            const int f = col / 6, j = col - f * 6;
            const float xx = sx[p * 3 + (j >= 3 ? j - 3 : j)] * (float)(1 << f);
            val = (j < 3) ? sinf(xx) : cosf(xx);
        }
        buf[p * LSTR + col] = (bf16)val;
    }
    __syncthreads();

    layer_fused<2>(buf, pin + (size_t)c * 16384, b_in + c * 256, lane, w);
    layer_fused<8>(buf, pmid + (size_t)(c * 3 + 0) * 65536, b_mid + (c * 3 + 0) * 256, lane, w);
    layer_fused<8>(buf, pmid + (size_t)(c * 3 + 1) * 65536, b_mid + (c * 3 + 1) * 256, lane, w);
    layer_fused<8>(buf, pmid + (size_t)(c * 3 + 2) * 65536, b_mid + (c * 3 + 2) * 256, lane, w);

    // Final 256 -> 3 + tanh in fp32 VALU (too thin for MFMA).
    if (tid < 192) {
        const int p = tid & 63, o = tid >> 6;
        const bf16* hp = buf + p * LSTR;
        const float* wr = woutw + (c * 3 + o) * 256;
        float s = b_out[c * 3 + o];
        for (int k = 0; k < 256; k += 8) {
            const bf16x8 hv = *(const bf16x8*)(hp + k);
            const float4* wv = (const float4*)(wr + k);
            const float4 w0 = wv[0], w1 = wv[1];
            s += (float)hv[0] * w0.x + (float)hv[1] * w0.y + (float)hv[2] * w0.z + (float)hv[3] * w0.w
               + (float)hv[4] * w1.x + (float)hv[5] * w1.y + (float)hv[6] * w1.z + (float)hv[7] * w1.w;
        }
        if (s0 + p < count) out[(size_t)sidx[p] * 3 + o] = tanhf(s);
    }
}

extern "C" void kernel_launch(void* const* d_in, const int* in_sizes, int n_in,
                              void* d_out, int out_size, void* d_ws, size_t ws_size,
                              hipStream_t stream) {
    const float* X     = (const float*)d_in[0];
    const int*   cid   = (const int*)d_in[1];
    const float* V_in  = (const float*)d_in[2];
    const float* g_in  = (const float*)d_in[3];
    const float* b_in  = (const float*)d_in[4];
    const float* V_mid = (const float*)d_in[5];
    const float* g_mid = (const float*)d_in[6];
    const float* b_mid = (const float*)d_in[7];
    const float* V_out = (const float*)d_in[8];
    const float* g_out = (const float*)d_in[9];
    const float* b_out = (const float*)d_in[10];
    float* out = (float*)d_out;
    const int N = in_sizes[0] / 3;   // 65536

    char* ws = (char*)d_ws;
    int*   cursor = (int*)ws;
    int*   order  = (int*)(ws + OFF_ORDER);
    bf16*  pin    = (bf16*)(ws + OFF_PIN);
    bf16*  pmid   = (bf16*)(ws + OFF_PMID);
    float* woutw  = (float*)(ws + OFF_WOUT);

    zero_cursor<<<1, 64, 0, stream>>>(cursor);
    scatter_kernel<<<N / 256, 256, 0, stream>>>(cid, cursor, order);
    const int prep_blocks = NCLUS * HDIM + NCLUS * 3 * HDIM + NCLUS * 3;  // 8216
    prep_kernel<<<prep_blocks, 256, 0, stream>>>(V_in, g_in, V_mid, g_mid, V_out, g_out,
                                                 pin, pmid, woutw);
    mlp_kernel<<<NCLUS * TPC, 256, 0, stream>>>(X, b_in, b_mid, b_out, cursor, order,
                                                pin, pmid, woutw, out);
}

// Round 3
// 134.049 us; speedup vs baseline: 1.6169x; 1.6169x over previous
//
#include <hip/hip_runtime.h>

typedef __bf16 bf16;
typedef __bf16 bf16x8 __attribute__((ext_vector_type(8)));
typedef __bf16 bf16x4 __attribute__((ext_vector_type(4)));
typedef float  f32x4  __attribute__((ext_vector_type(4)));

constexpr int NCLUS  = 8;
constexpr int HDIM   = 256;
constexpr int DIN    = 36;
constexpr int SEGCAP = 16384;          // per-cluster index capacity (mean 8192)
constexpr int TPC    = SEGCAP / 64;    // 256 tiles per cluster
constexpr int LSTR   = 264;            // LDS row stride bf16 — MUST be >= 256 (row width!).
                                       // 528 B/row = 132 dwords == 4 mod 32 -> 2-way banks (free).
                                       // Round-2 bug: LSTR=248 < 256 aliased cols 248..255 into
                                       // the next row -> absmax 0.37.

// ---------------- workspace layout (bytes) ----------------
constexpr size_t OFF_ORDER = 256;
constexpr size_t OFF_PIN   = OFF_ORDER + (size_t)NCLUS * SEGCAP * 4;
constexpr size_t OFF_PMID  = OFF_PIN + (size_t)NCLUS * 64 * 256 * 2;
constexpr size_t OFF_WOUT  = OFF_PMID + (size_t)NCLUS * 3 * 256 * 256 * 2;

// Partition point indices by cluster.
__global__ void scatter_kernel(const int* __restrict__ cid, int* __restrict__ cursor,
                               int* __restrict__ order) {
    __shared__ int lhist[NCLUS];
    __shared__ int lbase[NCLUS];
    const int tid = threadIdx.x;
    const int i = blockIdx.x * 256 + tid;
    if (tid < NCLUS) lhist[tid] = 0;
    __syncthreads();
    const int c = cid[i];
    const int my = atomicAdd(&lhist[c], 1);
    __syncthreads();
    if (tid < NCLUS) lbase[tid] = atomicAdd(&cursor[tid], lhist[tid]);
    __syncthreads();
    const int pos = lbase[c] + my;
    if (pos < SEGCAP) order[c * SEGCAP + pos] = i;
}

// Weight-norm + pack into MFMA A-fragment order (one WAVE per weight row, shuffle
// reduction, no block barriers). Fragment map: for row m, element k:
//   lane = ((k&31)>>3)*16 + (m&15), j = k&7, idx = ((k>>5)*16 + (m>>4))*512 + lane*8 + j.
__global__ void prep_kernel(const float* __restrict__ V_in,  const float* __restrict__ g_in,
                            const float* __restrict__ V_mid, const float* __restrict__ g_mid,
                            const float* __restrict__ V_out, const float* __restrict__ g_out,
                            bf16* __restrict__ pin, bf16* __restrict__ pmid,
                            float* __restrict__ woutw) {
    const int wv = threadIdx.x >> 6, lane = threadIdx.x & 63;
    const int row = blockIdx.x * 4 + wv;
    if (row >= NCLUS * HDIM + NCLUS * 3 * HDIM + NCLUS * 3) return;

    if (row < NCLUS * HDIM) {                                // input layer: [C,H,36]
        const int c = row >> 8, m = row & 255;
        const float* vrow = V_in + (size_t)row * DIN;
        float v = (lane < DIN) ? vrow[lane] : 0.f;
        float ss = v * v;
#pragma unroll
        for (int off = 32; off; off >>= 1) ss += __shfl_xor(ss, off);
        const float scale = g_in[row] / sqrtf(ss);
        const int k = lane;
        const int fl = (((k & 31) >> 3) << 4) | (m & 15);
        const int idx = ((k >> 5) * 16 + (m >> 4)) * 512 + fl * 8 + (k & 7);
        pin[(size_t)c * 16384 + idx] = (bf16)(v * scale);
    } else if (row < NCLUS * HDIM + NCLUS * 3 * HDIM) {      // mid: [C,3,H,H]
        const int r2 = row - NCLUS * HDIM;
        const int cl = r2 >> 8, m = r2 & 255;
        const float4 v4 = *(const float4*)(V_mid + (size_t)r2 * 256 + lane * 4);
        float ss = v4.x * v4.x + v4.y * v4.y + v4.z * v4.z + v4.w * v4.w;
#pragma unroll
        for (int off = 32; off; off >>= 1) ss += __shfl_xor(ss, off);
        const float scale = g_mid[cl * 256 + m] / sqrtf(ss);
        const int k = lane * 4;
        const int fl = (((k & 31) >> 3) << 4) | (m & 15);
        const int idx = ((k >> 5) * 16 + (m >> 4)) * 512 + fl * 8 + (k & 7);
        bf16x4 o = { (bf16)(v4.x * scale), (bf16)(v4.y * scale),
                     (bf16)(v4.z * scale), (bf16)(v4.w * scale) };
        *(bf16x4*)(pmid + (size_t)cl * 65536 + idx) = o;     // idx%8 in {0,4} -> 8 B aligned
    } else {                                                 // out rows: [C,3,H]
        const int r3 = row - (NCLUS * HDIM + NCLUS * 3 * HDIM);
        const float4 v4 = *(const float4*)(V_out + (size_t)r3 * 256 + lane * 4);
        float ss = v4.x * v4.x + v4.y * v4.y + v4.z * v4.z + v4.w * v4.w;
#pragma unroll
        for (int off = 32; off; off >>= 1) ss += __shfl_xor(ss, off);
        const float scale = g_out[r3] / sqrtf(ss);
        float4 o = { v4.x * scale, v4.y * scale, v4.z * scale, v4.w * scale };
        *(float4*)(woutw + r3 * 256 + lane * 4) = o;
    }
}

// One layer in place: H[64,256] = relu(W @ H^T)^T. A = weights (prepacked, global),
// B = activations (LDS). Wave w owns outcols [64w,64w+64) x all 64 points.
// A-frags software-pipelined 2 ksteps deep (hides ~200cyc L2 latency).
// D layout: col(lane&15)=point, row(quad*4+reg)=outcol -> epilogue = 16 x ds_write_b64.
template <int KSTEPS>
__device__ __forceinline__ void layer_fused(bf16* __restrict__ buf,
                                            const bf16* __restrict__ wp,
                                            const float* __restrict__ bias,
                                            int lane, int w) {
    const int quad = lane >> 4, l15 = lane & 15;
    f32x4 acc[4][4];   // [mt][nt]
#pragma unroll
    for (int mt = 0; mt < 4; mt++)
#pragma unroll
        for (int nt = 0; nt < 4; nt++) acc[mt][nt] = (f32x4){0.f, 0.f, 0.f, 0.f};

    bf16x8 a[3][4];
#pragma unroll
    for (int mt = 0; mt < 4; mt++)
        a[0][mt] = *(const bf16x8*)(wp + (size_t)((0 * 16 + (4 * w + mt)) * 512 + lane * 8));
    if (KSTEPS > 1)
#pragma unroll
        for (int mt = 0; mt < 4; mt++)
            a[1][mt] = *(const bf16x8*)(wp + (size_t)((1 * 16 + (4 * w + mt)) * 512 + lane * 8));

#pragma unroll
    for (int ks = 0; ks < KSTEPS; ks++) {
        if (ks + 2 < KSTEPS) {
#pragma unroll
            for (int mt = 0; mt < 4; mt++)
                a[(ks + 2) % 3][mt] =
                    *(const bf16x8*)(wp + (size_t)(((ks + 2) * 16 + (4 * w + mt)) * 512 + lane * 8));
        }
        bf16x8 b[4];
#pragma unroll
        for (int nt = 0; nt < 4; nt++)
            b[nt] = *(const bf16x8*)(buf + (nt * 16 + l15) * LSTR + ks * 32 + quad * 8);
#pragma unroll
        for (int mt = 0; mt < 4; mt++)
#pragma unroll
            for (int nt = 0; nt < 4; nt++)
                acc[mt][nt] = __builtin_amdgcn_mfma_f32_16x16x32_bf16(a[ks % 3][mt], b[nt],
                                                                      acc[mt][nt], 0, 0, 0);
    }
    __syncthreads();   // all reads of buf done
#pragma unroll
    for (int mt = 0; mt < 4; mt++) {
        const int m0 = 64 * w + mt * 16 + quad * 4;
        const float4 bv = *(const float4*)(bias + m0);
#pragma unroll
        for (int nt = 0; nt < 4; nt++) {
            const int p = nt * 16 + l15;
            float v0 = acc[mt][nt][0] + bv.x, v1 = acc[mt][nt][1] + bv.y;
            float v2 = acc[mt][nt][2] + bv.z, v3 = acc[mt][nt][3] + bv.w;
            bf16x4 o = { (bf16)(v0 > 0.f ? v0 : 0.f), (bf16)(v1 > 0.f ? v1 : 0.f),
                         (bf16)(v2 > 0.f ? v2 : 0.f), (bf16)(v3 > 0.f ? v3 : 0.f) };
            *(bf16x4*)(buf + p * LSTR + m0) = o;   // 8-B aligned (LSTR*2=528, m0*2 mult of 8)
        }
    }
    __syncthreads();   // buf ready for next layer
}

__global__ __launch_bounds__(256, 3) void mlp_kernel(
    const float* __restrict__ X,
    const float* __restrict__ b_in, const float* __restrict__ b_mid,
    const float* __restrict__ b_out,
    const int* __restrict__ counts, const int* __restrict__ order,
    const bf16* __restrict__ pin, const bf16* __restrict__ pmid,
    const float* __restrict__ woutw, float* __restrict__ out) {
    const int c = blockIdx.x >> 8;
    const int tile = blockIdx.x & (TPC - 1);
    const int count = counts[c];
    const int s0 = tile * 64;
    if (s0 >= count) return;

    __shared__ __align__(16) bf16 buf[64 * LSTR];   // 33792 B
    __shared__ int sidx[64];
    __shared__ float sx[192];

    const int tid = threadIdx.x;
    const int lane = tid & 63;
    const int w = tid >> 6;

    if (tid < 64) {
        const int g = s0 + tid;
        sidx[tid] = order[c * SEGCAP + (g < count ? g : s0)];
    }
    __syncthreads();
    if (tid < 192) sx[tid] = X[(size_t)sidx[tid / 3] * 3 + tid % 3];
    __syncthreads();

    // Positional encoding -> bf16, cols 36..63 zero (weights zero there too).
    for (int v = tid; v < 64 * 64; v += 256) {
        const int p = v >> 6, col = v & 63;
        float val = 0.f;
        if (col < DIN) {
            const int f = col / 6, j = col - f * 6;
            const float xx = sx[p * 3 + (j >= 3 ? j - 3 : j)] * (float)(1 << f);
            val = (j < 3) ? sinf(xx) : cosf(xx);
        }
        buf[p * LSTR + col] = (bf16)val;
    }
    __syncthreads();

    layer_fused<2>(buf, pin + (size_t)c * 16384, b_in + c * 256, lane, w);
    layer_fused<8>(buf, pmid + (size_t)(c * 3 + 0) * 65536, b_mid + (c * 3 + 0) * 256, lane, w);
    layer_fused<8>(buf, pmid + (size_t)(c * 3 + 1) * 65536, b_mid + (c * 3 + 1) * 256, lane, w);
    layer_fused<8>(buf, pmid + (size_t)(c * 3 + 2) * 65536, b_mid + (c * 3 + 2) * 256, lane, w);

    // Final 256 -> 3 + tanh, fp32 VALU.
    if (tid < 192) {
        const int p = tid & 63, o = tid >> 6;
        const bf16* hp = buf + p * LSTR;
        const float* wr = woutw + (c * 3 + o) * 256;
        float s = b_out[c * 3 + o];
        for (int k = 0; k < 256; k += 8) {
            const bf16x8 hv = *(const bf16x8*)(hp + k);
            const float4* wvp = (const float4*)(wr + k);
            const float4 w0 = wvp[0], w1 = wvp[1];
            s += (float)hv[0] * w0.x + (float)hv[1] * w0.y + (float)hv[2] * w0.z + (float)hv[3] * w0.w
               + (float)hv[4] * w1.x + (float)hv[5] * w1.y + (float)hv[6] * w1.z + (float)hv[7] * w1.w;
        }
        if (s0 + p < count) out[(size_t)sidx[p] * 3 + o] = tanhf(s);
    }
}

extern "C" void kernel_launch(void* const* d_in, const int* in_sizes, int n_in,
                              void* d_out, int out_size, void* d_ws, size_t ws_size,
                              hipStream_t stream) {
    const float* X     = (const float*)d_in[0];
    const int*   cid   = (const int*)d_in[1];
    const float* V_in  = (const float*)d_in[2];
    const float* g_in  = (const float*)d_in[3];
    const float* b_in  = (const float*)d_in[4];
    const float* V_mid = (const float*)d_in[5];
    const float* g_mid = (const float*)d_in[6];
    const float* b_mid = (const float*)d_in[7];
    const float* V_out = (const float*)d_in[8];
    const float* g_out = (const float*)d_in[9];
    const float* b_out = (const float*)d_in[10];
    float* out = (float*)d_out;
    const int N = in_sizes[0] / 3;   // 65536

    char* ws = (char*)d_ws;
    int*   cursor = (int*)ws;
    int*   order  = (int*)(ws + OFF_ORDER);
    bf16*  pin    = (bf16*)(ws + OFF_PIN);
    bf16*  pmid   = (bf16*)(ws + OFF_PMID);
    float* woutw  = (float*)(ws + OFF_WOUT);

    hipMemsetAsync(cursor, 0, NCLUS * sizeof(int), stream);
    scatter_kernel<<<N / 256, 256, 0, stream>>>(cid, cursor, order);
    const int rows = NCLUS * HDIM + NCLUS * 3 * HDIM + NCLUS * 3;  // 8216
    prep_kernel<<<(rows + 3) / 4, 256, 0, stream>>>(V_in, g_in, V_mid, g_mid, V_out, g_out,
                                                    pin, pmid, woutw);
    mlp_kernel<<<NCLUS * TPC, 256, 0, stream>>>(X, b_in, b_mid, b_out, cursor, order,
                                                pin, pmid, woutw, out);
}

// Round 4
// 128.780 us; speedup vs baseline: 1.6830x; 1.0409x over previous
//
#include <hip/hip_runtime.h>

typedef __bf16 bf16;
typedef __bf16 bf16x8 __attribute__((ext_vector_type(8)));
typedef __bf16 bf16x4 __attribute__((ext_vector_type(4)));
typedef float  f32x4  __attribute__((ext_vector_type(4)));

constexpr int NCLUS  = 8;
constexpr int HDIM   = 256;
constexpr int DIN    = 36;
constexpr int SEGCAP = 16384;          // per-cluster index capacity (mean 8192)
constexpr int LSTR   = 264;            // LDS row stride bf16 — MUST be >= 256 (round-2 bug).
                                       // 528 B/row = 132 dw == 4 mod 32 -> 2-way banks (free).
constexpr int CURPAD = 32;             // cursor entries 128 B apart -> no same-line atomic pileup
constexpr int SCAT_BLKS = 64;          // 64 x 1024 threads = 65536 points
constexpr int PREP_ROWS = NCLUS * HDIM + NCLUS * 3 * HDIM + NCLUS * 3;   // 8216
constexpr int PREP_BLKS = (PREP_ROWS + 15) / 16;                          // 16 waves/block
constexpr int MLP_BLKS  = 65536 / 64 + NCLUS;                             // exact-tile upper bound

// ---------------- workspace layout (bytes) ----------------
constexpr size_t OFF_ORDER = 4096;     // cursor occupies [0, 1024)
constexpr size_t OFF_PIN   = OFF_ORDER + (size_t)NCLUS * SEGCAP * 4;
constexpr size_t OFF_PMID  = OFF_PIN + (size_t)NCLUS * 64 * 256 * 2;
constexpr size_t OFF_WOUT  = OFF_PMID + (size_t)NCLUS * 3 * 256 * 256 * 2;

// Fused setup: blocks [0,64) partition points by cluster; the rest weight-norm+pack.
// Scatter: per-wave ballot ranks (no LDS atomics for ranking), 8 LDS atomics/wave for
// wave bases, 8 global atomics/block on 128B-padded counters (parallel across TCCs).
// Prep fragment map (row m, element k): lane=((k&31)>>3)*16+(m&15), j=k&7,
//   idx = ((k>>5)*16 + (m>>4))*512 + lane*8 + j.
__global__ __launch_bounds__(1024) void setup_kernel(
    const int* __restrict__ cid, int* __restrict__ cursor, int* __restrict__ order,
    const float* __restrict__ V_in,  const float* __restrict__ g_in,
    const float* __restrict__ V_mid, const float* __restrict__ g_mid,
    const float* __restrict__ V_out, const float* __restrict__ g_out,
    bf16* __restrict__ pin, bf16* __restrict__ pmid, float* __restrict__ woutw) {
    const int tid = threadIdx.x;
    const int wv = tid >> 6, lane = tid & 63;

    if (blockIdx.x < SCAT_BLKS) {
        __shared__ int bhist[NCLUS];
        __shared__ int wbase[16][NCLUS];
        __shared__ int gbase[NCLUS];
        const int i = blockIdx.x * 1024 + tid;
        const int c = cid[i];
        if (tid < NCLUS) bhist[tid] = 0;
        __syncthreads();
        unsigned long long masks[NCLUS];
#pragma unroll
        for (int cc = 0; cc < NCLUS; cc++) masks[cc] = __ballot(c == cc);
        const int rank = __popcll(masks[c] & ((1ull << lane) - 1ull));
        if (lane < NCLUS) wbase[wv][lane] = atomicAdd(&bhist[lane], __popcll(masks[lane]));
        __syncthreads();
        if (tid < NCLUS) gbase[tid] = atomicAdd(&cursor[tid * CURPAD], bhist[tid]);
        __syncthreads();
        const int pos = gbase[c] + wbase[wv][c] + rank;
        if (pos < SEGCAP) order[c * SEGCAP + pos] = i;
        return;
    }

    const int row = (blockIdx.x - SCAT_BLKS) * 16 + wv;
    if (row >= PREP_ROWS) return;

    if (row < NCLUS * HDIM) {                                // input layer: [C,H,36]
        const int c = row >> 8, m = row & 255;
        const float* vrow = V_in + (size_t)row * DIN;
        float v = (lane < DIN) ? vrow[lane] : 0.f;
        float ss = v * v;
#pragma unroll
        for (int off = 32; off; off >>= 1) ss += __shfl_xor(ss, off);
        const float scale = g_in[row] / sqrtf(ss);
        const int k = lane;
        const int fl = (((k & 31) >> 3) << 4) | (m & 15);
        const int idx = ((k >> 5) * 16 + (m >> 4)) * 512 + fl * 8 + (k & 7);
        pin[(size_t)c * 16384 + idx] = (bf16)(v * scale);
    } else if (row < NCLUS * HDIM + NCLUS * 3 * HDIM) {      // mid: [C,3,H,H]
        const int r2 = row - NCLUS * HDIM;
        const int cl = r2 >> 8, m = r2 & 255;
        const float4 v4 = *(const float4*)(V_mid + (size_t)r2 * 256 + lane * 4);
        float ss = v4.x * v4.x + v4.y * v4.y + v4.z * v4.z + v4.w * v4.w;
#pragma unroll
        for (int off = 32; off; off >>= 1) ss += __shfl_xor(ss, off);
        const float scale = g_mid[cl * 256 + m] / sqrtf(ss);
        const int k = lane * 4;
        const int fl = (((k & 31) >> 3) << 4) | (m & 15);
        const int idx = ((k >> 5) * 16 + (m >> 4)) * 512 + fl * 8 + (k & 7);
        bf16x4 o = { (bf16)(v4.x * scale), (bf16)(v4.y * scale),
                     (bf16)(v4.z * scale), (bf16)(v4.w * scale) };
        *(bf16x4*)(pmid + (size_t)cl * 65536 + idx) = o;     // idx%8 in {0,4} -> 8 B aligned
    } else {                                                 // out rows: [C,3,H]
        const int r3 = row - (NCLUS * HDIM + NCLUS * 3 * HDIM);
        const float4 v4 = *(const float4*)(V_out + (size_t)r3 * 256 + lane * 4);
        float ss = v4.x * v4.x + v4.y * v4.y + v4.z * v4.z + v4.w * v4.w;
#pragma unroll
        for (int off = 32; off; off >>= 1) ss += __shfl_xor(ss, off);
        const float scale = g_out[r3] / sqrtf(ss);
        float4 o = { v4.x * scale, v4.y * scale, v4.z * scale, v4.w * scale };
        *(float4*)(woutw + r3 * 256 + lane * 4) = o;
    }
}

// One layer in place: H[64,256] = relu(W @ H^T)^T. A = weights (prepacked, global),
// B = activations (LDS). Wave w owns outcols [64w,64w+64) x all 64 points.
// A-frags software-pipelined 2 ksteps ahead (hides ~200cyc L2 latency).
// D layout: col(lane&15)=point, row(quad*4+reg)=outcol -> epilogue = 16 x ds_write_b64.
template <int KSTEPS>
__device__ __forceinline__ void layer_fused(bf16* __restrict__ buf,
                                            const bf16* __restrict__ wp,
                                            const float* __restrict__ bias,
                                            int lane, int w) {
    const int quad = lane >> 4, l15 = lane & 15;
    f32x4 acc[4][4];   // [mt][nt]
#pragma unroll
    for (int mt = 0; mt < 4; mt++)
#pragma unroll
        for (int nt = 0; nt < 4; nt++) acc[mt][nt] = (f32x4){0.f, 0.f, 0.f, 0.f};

    bf16x8 a[3][4];
#pragma unroll
    for (int mt = 0; mt < 4; mt++)
        a[0][mt] = *(const bf16x8*)(wp + (size_t)((0 * 16 + (4 * w + mt)) * 512 + lane * 8));
    if (KSTEPS > 1)
#pragma unroll
        for (int mt = 0; mt < 4; mt++)
            a[1][mt] = *(const bf16x8*)(wp + (size_t)((1 * 16 + (4 * w + mt)) * 512 + lane * 8));

#pragma unroll
    for (int ks = 0; ks < KSTEPS; ks++) {
        if (ks + 2 < KSTEPS) {
#pragma unroll
            for (int mt = 0; mt < 4; mt++)
                a[(ks + 2) % 3][mt] =
                    *(const bf16x8*)(wp + (size_t)(((ks + 2) * 16 + (4 * w + mt)) * 512 + lane * 8));
        }
        bf16x8 b[4];
#pragma unroll
        for (int nt = 0; nt < 4; nt++)
            b[nt] = *(const bf16x8*)(buf + (nt * 16 + l15) * LSTR + ks * 32 + quad * 8);
#pragma unroll
        for (int mt = 0; mt < 4; mt++)
#pragma unroll
            for (int nt = 0; nt < 4; nt++)
                acc[mt][nt] = __builtin_amdgcn_mfma_f32_16x16x32_bf16(a[ks % 3][mt], b[nt],
                                                                      acc[mt][nt], 0, 0, 0);
    }
    __syncthreads();   // all reads of buf done
#pragma unroll
    for (int mt = 0; mt < 4; mt++) {
        const int m0 = 64 * w + mt * 16 + quad * 4;
        const float4 bv = *(const float4*)(bias + m0);
#pragma unroll
        for (int nt = 0; nt < 4; nt++) {
            const int p = nt * 16 + l15;
            float v0 = acc[mt][nt][0] + bv.x, v1 = acc[mt][nt][1] + bv.y;
            float v2 = acc[mt][nt][2] + bv.z, v3 = acc[mt][nt][3] + bv.w;
            bf16x4 o = { (bf16)(v0 > 0.f ? v0 : 0.f), (bf16)(v1 > 0.f ? v1 : 0.f),
                         (bf16)(v2 > 0.f ? v2 : 0.f), (bf16)(v3 > 0.f ? v3 : 0.f) };
            *(bf16x4*)(buf + p * LSTR + m0) = o;   // 8-B aligned
        }
    }
    __syncthreads();   // buf ready for next layer
}

__global__ __launch_bounds__(256, 3) void mlp_kernel(
    const float* __restrict__ X,
    const float* __restrict__ b_in, const float* __restrict__ b_mid,
    const float* __restrict__ b_out,
    const int* __restrict__ counts, const int* __restrict__ order,
    const bf16* __restrict__ pin, const bf16* __restrict__ pmid,
    const float* __restrict__ woutw, float* __restrict__ out) {
    // Exact tile scheduling: map blockIdx -> (cluster, tile) by prefix-scanning the
    // 8 padded counts. No dead blocks (round-3: half the grid exited instantly).
    int c = -1, tile = 0, count = 0;
    {
        int base = 0;
#pragma unroll
        for (int cc = 0; cc < NCLUS; cc++) {
            int cnt = counts[cc * CURPAD];
            if (cnt > SEGCAP) cnt = SEGCAP;
            const int nt = (cnt + 63) >> 6;
            if ((int)blockIdx.x >= base && (int)blockIdx.x < base + nt) {
                c = cc; tile = blockIdx.x - base; count = cnt;
            }
            base += nt;
        }
    }
    if (c < 0) return;
    const int s0 = tile * 64;

    __shared__ __align__(16) bf16 buf[64 * LSTR];   // 33792 B
    __shared__ int sidx[64];
    __shared__ float sx[192];

    const int tid = threadIdx.x;
    const int lane = tid & 63;
    const int w = tid >> 6;

    if (tid < 64) {
        const int g = s0 + tid;
        sidx[tid] = order[c * SEGCAP + (g < count ? g : s0)];
    }
    __syncthreads();
    if (tid < 192) sx[tid] = X[(size_t)sidx[tid / 3] * 3 + tid % 3];
    __syncthreads();

    // Positional encoding -> bf16, cols 36..63 zero (weights zero there too).
    for (int v = tid; v < 64 * 64; v += 256) {
        const int p = v >> 6, col = v & 63;
        float val = 0.f;
        if (col < DIN) {
            const int f = col / 6, j = col - f * 6;
            const float xx = sx[p * 3 + (j >= 3 ? j - 3 : j)] * (float)(1 << f);
            val = (j < 3) ? sinf(xx) : cosf(xx);
        }
        buf[p * LSTR + col] = (bf16)val;
    }
    __syncthreads();

    layer_fused<2>(buf, pin + (size_t)c * 16384, b_in + c * 256, lane, w);
    layer_fused<8>(buf, pmid + (size_t)(c * 3 + 0) * 65536, b_mid + (c * 3 + 0) * 256, lane, w);
    layer_fused<8>(buf, pmid + (size_t)(c * 3 + 1) * 65536, b_mid + (c * 3 + 1) * 256, lane, w);
    layer_fused<8>(buf, pmid + (size_t)(c * 3 + 2) * 65536, b_mid + (c * 3 + 2) * 256, lane, w);

    // Final 256 -> 3 + tanh, fp32 VALU.
    if (tid < 192) {
        const int p = tid & 63, o = tid >> 6;
        const bf16* hp = buf + p * LSTR;
        const float* wr = woutw + (c * 3 + o) * 256;
        float s = b_out[c * 3 + o];
        for (int k = 0; k < 256; k += 8) {
            const bf16x8 hv = *(const bf16x8*)(hp + k);
            const float4* wvp = (const float4*)(wr + k);
            const float4 w0 = wvp[0], w1 = wvp[1];
            s += (float)hv[0] * w0.x + (float)hv[1] * w0.y + (float)hv[2] * w0.z + (float)hv[3] * w0.w
               + (float)hv[4] * w1.x + (float)hv[5] * w1.y + (float)hv[6] * w1.z + (float)hv[7] * w1.w;
        }
        if (s0 + p < count) out[(size_t)sidx[p] * 3 + o] = tanhf(s);
    }
}

extern "C" void kernel_launch(void* const* d_in, const int* in_sizes, int n_in,
                              void* d_out, int out_size, void* d_ws, size_t ws_size,
                              hipStream_t stream) {
    const float* X     = (const float*)d_in[0];
    const int*   cid   = (const int*)d_in[1];
    const float* V_in  = (const float*)d_in[2];
    const float* g_in  = (const float*)d_in[3];
    const float* b_in  = (const float*)d_in[4];
    const float* V_mid = (const float*)d_in[5];
    const float* g_mid = (const float*)d_in[6];
    const float* b_mid = (const float*)d_in[7];
    const float* V_out = (const float*)d_in[8];
    const float* g_out = (const float*)d_in[9];
    const float* b_out = (const float*)d_in[10];
    float* out = (float*)d_out;

    char* ws = (char*)d_ws;
    int*   cursor = (int*)ws;                    // NCLUS entries, 128 B apart
    int*   order  = (int*)(ws + OFF_ORDER);
    bf16*  pin    = (bf16*)(ws + OFF_PIN);
    bf16*  pmid   = (bf16*)(ws + OFF_PMID);
    float* woutw  = (float*)(ws + OFF_WOUT);

    hipMemsetAsync(cursor, 0, NCLUS * CURPAD * sizeof(int), stream);
    setup_kernel<<<SCAT_BLKS + PREP_BLKS, 1024, 0, stream>>>(
        cid, cursor, order, V_in, g_in, V_mid, g_mid, V_out, g_out, pin, pmid, woutw);
    mlp_kernel<<<MLP_BLKS, 256, 0, stream>>>(X, b_in, b_mid, b_out, cursor, order,
                                             pin, pmid, woutw, out);
}

// Round 5
// 125.478 us; speedup vs baseline: 1.7273x; 1.0263x over previous
//
#include <hip/hip_runtime.h>

typedef __bf16 bf16;
typedef __bf16 bf16x8 __attribute__((ext_vector_type(8)));
typedef __bf16 bf16x4 __attribute__((ext_vector_type(4)));
typedef float  f32x4  __attribute__((ext_vector_type(4)));

constexpr int NCLUS  = 8;
constexpr int HDIM   = 256;
constexpr int DIN    = 36;
constexpr int SEGCAP = 16384;          // per-cluster index capacity (mean 8192)
constexpr int LSTR   = 264;            // LDS row stride bf16 — MUST be >= 256 (round-2 bug).
                                       // 528 B/row = 132 dw == 4 mod 32 -> 2-way banks (free).
constexpr int CURPAD = 32;             // cursor entries 128 B apart
constexpr int SCAT_BLKS = 64;          // 64 x 1024 threads = 65536 points
constexpr int PREP_ROWS = NCLUS * HDIM + NCLUS * 3 * HDIM + NCLUS * 3;   // 8216
constexpr int PREP_BLKS = (PREP_ROWS + 15) / 16;                          // 16 waves/block
constexpr int MAXT   = 160;            // tiles/cluster covered (mean 128, +8.6 sigma)
constexpr int MLP_BLKS = NCLUS * MAXT; // 1280; c = blockIdx&7 -> cluster pinned to one XCD

// ---------------- workspace layout (bytes) ----------------
constexpr size_t OFF_ORDER = 4096;     // cursor occupies [0, 1024)
constexpr size_t OFF_PIN   = OFF_ORDER + (size_t)NCLUS * SEGCAP * 4;
constexpr size_t OFF_PMID  = OFF_PIN + (size_t)NCLUS * 64 * 256 * 2;
constexpr size_t OFF_WOUT  = OFF_PMID + (size_t)NCLUS * 3 * 256 * 256 * 2;

// Fused setup: blocks [0,64) partition points by cluster; the rest weight-norm+pack.
// Prep fragment map (row m, element k): lane=((k&31)>>3)*16+(m&15), j=k&7,
//   idx = ((k>>5)*16 + (m>>4))*512 + lane*8 + j.
__global__ __launch_bounds__(1024) void setup_kernel(
    const int* __restrict__ cid, int* __restrict__ cursor, int* __restrict__ order,
    const float* __restrict__ V_in,  const float* __restrict__ g_in,
    const float* __restrict__ V_mid, const float* __restrict__ g_mid,
    const float* __restrict__ V_out, const float* __restrict__ g_out,
    bf16* __restrict__ pin, bf16* __restrict__ pmid, float* __restrict__ woutw) {
    const int tid = threadIdx.x;
    const int wv = tid >> 6, lane = tid & 63;

    if (blockIdx.x < SCAT_BLKS) {
        __shared__ int bhist[NCLUS];
        __shared__ int wbase[16][NCLUS];
        __shared__ int gbase[NCLUS];
        const int i = blockIdx.x * 1024 + tid;
        const int c = cid[i];
        if (tid < NCLUS) bhist[tid] = 0;
        __syncthreads();
        unsigned long long masks[NCLUS];
#pragma unroll
        for (int cc = 0; cc < NCLUS; cc++) masks[cc] = __ballot(c == cc);
        const int rank = __popcll(masks[c] & ((1ull << lane) - 1ull));
        if (lane < NCLUS) wbase[wv][lane] = atomicAdd(&bhist[lane], __popcll(masks[lane]));
        __syncthreads();
        if (tid < NCLUS) gbase[tid] = atomicAdd(&cursor[tid * CURPAD], bhist[tid]);
        __syncthreads();
        const int pos = gbase[c] + wbase[wv][c] + rank;
        if (pos < SEGCAP) order[c * SEGCAP + pos] = i;
        return;
    }

    const int row = (blockIdx.x - SCAT_BLKS) * 16 + wv;
    if (row >= PREP_ROWS) return;

    if (row < NCLUS * HDIM) {                                // input layer: [C,H,36]
        const int c = row >> 8, m = row & 255;
        const float* vrow = V_in + (size_t)row * DIN;
        float v = (lane < DIN) ? vrow[lane] : 0.f;
        float ss = v * v;
#pragma unroll
        for (int off = 32; off; off >>= 1) ss += __shfl_xor(ss, off);
        const float scale = g_in[row] / sqrtf(ss);
        const int k = lane;
        const int fl = (((k & 31) >> 3) << 4) | (m & 15);
        const int idx = ((k >> 5) * 16 + (m >> 4)) * 512 + fl * 8 + (k & 7);
        pin[(size_t)c * 16384 + idx] = (bf16)(v * scale);
    } else if (row < NCLUS * HDIM + NCLUS * 3 * HDIM) {      // mid: [C,3,H,H]
        const int r2 = row - NCLUS * HDIM;
        const int cl = r2 >> 8, m = r2 & 255;
        const float4 v4 = *(const float4*)(V_mid + (size_t)r2 * 256 + lane * 4);
        float ss = v4.x * v4.x + v4.y * v4.y + v4.z * v4.z + v4.w * v4.w;
#pragma unroll
        for (int off = 32; off; off >>= 1) ss += __shfl_xor(ss, off);
        const float scale = g_mid[cl * 256 + m] / sqrtf(ss);
        const int k = lane * 4;
        const int fl = (((k & 31) >> 3) << 4) | (m & 15);
        const int idx = ((k >> 5) * 16 + (m >> 4)) * 512 + fl * 8 + (k & 7);
        bf16x4 o = { (bf16)(v4.x * scale), (bf16)(v4.y * scale),
                     (bf16)(v4.z * scale), (bf16)(v4.w * scale) };
        *(bf16x4*)(pmid + (size_t)cl * 65536 + idx) = o;     // idx%8 in {0,4} -> 8 B aligned
    } else {                                                 // out rows: [C,3,H]
        const int r3 = row - (NCLUS * HDIM + NCLUS * 3 * HDIM);
        const float4 v4 = *(const float4*)(V_out + (size_t)r3 * 256 + lane * 4);
        float ss = v4.x * v4.x + v4.y * v4.y + v4.z * v4.z + v4.w * v4.w;
#pragma unroll
        for (int off = 32; off; off >>= 1) ss += __shfl_xor(ss, off);
        const float scale = g_out[r3] / sqrtf(ss);
        float4 o = { v4.x * scale, v4.y * scale, v4.z * scale, v4.w * scale };
        *(float4*)(woutw + r3 * 256 + lane * 4) = o;
    }
}

// One layer in place: H[64,256] = relu(W @ H^T)^T. A = weights (prepacked, global,
// L2-resident on this block's XCD thanks to cluster->XCD pinning), B = activations
// (LDS). Wave w owns outcols [64w,64w+64) x all 64 points. A-frags software-pipelined
// 2 ksteps ahead (covers ~200cyc L2-hit latency).
// D layout: col(lane&15)=point, row(quad*4+reg)=outcol -> epilogue = 16 x ds_write_b64.
template <int KSTEPS>
__device__ __forceinline__ void layer_fused(bf16* __restrict__ buf,
                                            const bf16* __restrict__ wp,
                                            const float* __restrict__ bias,
                                            int lane, int w) {
    const int quad = lane >> 4, l15 = lane & 15;
    f32x4 acc[4][4];   // [mt][nt]
#pragma unroll
    for (int mt = 0; mt < 4; mt++)
#pragma unroll
        for (int nt = 0; nt < 4; nt++) acc[mt][nt] = (f32x4){0.f, 0.f, 0.f, 0.f};

    bf16x8 a[3][4];
#pragma unroll
    for (int mt = 0; mt < 4; mt++)
        a[0][mt] = *(const bf16x8*)(wp + (size_t)((0 * 16 + (4 * w + mt)) * 512 + lane * 8));
    if (KSTEPS > 1)
#pragma unroll
        for (int mt = 0; mt < 4; mt++)
            a[1][mt] = *(const bf16x8*)(wp + (size_t)((1 * 16 + (4 * w + mt)) * 512 + lane * 8));

#pragma unroll
    for (int ks = 0; ks < KSTEPS; ks++) {
        if (ks + 2 < KSTEPS) {
#pragma unroll
            for (int mt = 0; mt < 4; mt++)
                a[(ks + 2) % 3][mt] =
                    *(const bf16x8*)(wp + (size_t)(((ks + 2) * 16 + (4 * w + mt)) * 512 + lane * 8));
        }
        bf16x8 b[4];
#pragma unroll
        for (int nt = 0; nt < 4; nt++)
            b[nt] = *(const bf16x8*)(buf + (nt * 16 + l15) * LSTR + ks * 32 + quad * 8);
#pragma unroll
        for (int mt = 0; mt < 4; mt++)
#pragma unroll
            for (int nt = 0; nt < 4; nt++)
                acc[mt][nt] = __builtin_amdgcn_mfma_f32_16x16x32_bf16(a[ks % 3][mt], b[nt],
                                                                      acc[mt][nt], 0, 0, 0);
    }
    __syncthreads();   // all reads of buf done
#pragma unroll
    for (int mt = 0; mt < 4; mt++) {
        const int m0 = 64 * w + mt * 16 + quad * 4;
        const float4 bv = *(const float4*)(bias + m0);
#pragma unroll
        for (int nt = 0; nt < 4; nt++) {
            const int p = nt * 16 + l15;
            float v0 = acc[mt][nt][0] + bv.x, v1 = acc[mt][nt][1] + bv.y;
            float v2 = acc[mt][nt][2] + bv.z, v3 = acc[mt][nt][3] + bv.w;
            bf16x4 o = { (bf16)(v0 > 0.f ? v0 : 0.f), (bf16)(v1 > 0.f ? v1 : 0.f),
                         (bf16)(v2 > 0.f ? v2 : 0.f), (bf16)(v3 > 0.f ? v3 : 0.f) };
            *(bf16x4*)(buf + p * LSTR + m0) = o;   // 8-B aligned
        }
    }
    __syncthreads();   // buf ready for next layer
}

__global__ __launch_bounds__(256, 3) void mlp_kernel(
    const float* __restrict__ X,
    const float* __restrict__ b_in, const float* __restrict__ b_mid,
    const float* __restrict__ b_out,
    const int* __restrict__ counts, const int* __restrict__ order,
    const bf16* __restrict__ pin, const bf16* __restrict__ pmid,
    const float* __restrict__ woutw, float* __restrict__ out) {
    // Cluster->XCD pinning: blocks dispatch round-robin over the 8 XCDs, so
    // c = blockIdx&7 puts every tile of cluster c on XCD c -> its 428 KB of packed
    // weights stay resident in that XCD's 4 MB L2 (round-4: scattered clusters
    // refetched weights ~4x from HBM, FETCH 15.5 MB, 900-cyc misses unhidden).
    const int c = blockIdx.x & 7;
    const int tile = blockIdx.x >> 3;
    int count = counts[c * CURPAD];
    if (count > SEGCAP) count = SEGCAP;
    const int s0 = tile * 64;
    if (s0 >= count) return;

    __shared__ __align__(16) bf16 buf[64 * LSTR];   // 33792 B
    __shared__ int sidx[64];
    __shared__ float sx[192];

    const int tid = threadIdx.x;
    const int lane = tid & 63;
    const int w = tid >> 6;

    if (tid < 64) {
        const int g = s0 + tid;
        sidx[tid] = order[c * SEGCAP + (g < count ? g : s0)];
    }
    __syncthreads();
    if (tid < 192) sx[tid] = X[(size_t)sidx[tid / 3] * 3 + tid % 3];
    __syncthreads();

    // Positional encoding -> bf16, cols 36..63 zero (weights zero there too).
    for (int v = tid; v < 64 * 64; v += 256) {
        const int p = v >> 6, col = v & 63;
        float val = 0.f;
        if (col < DIN) {
            const int f = col / 6, j = col - f * 6;
            const float xx = sx[p * 3 + (j >= 3 ? j - 3 : j)] * (float)(1 << f);
            val = (j < 3) ? sinf(xx) : cosf(xx);
        }
        buf[p * LSTR + col] = (bf16)val;
    }
    __syncthreads();

    layer_fused<2>(buf, pin + (size_t)c * 16384, b_in + c * 256, lane, w);
    layer_fused<8>(buf, pmid + (size_t)(c * 3 + 0) * 65536, b_mid + (c * 3 + 0) * 256, lane, w);
    layer_fused<8>(buf, pmid + (size_t)(c * 3 + 1) * 65536, b_mid + (c * 3 + 1) * 256, lane, w);
    layer_fused<8>(buf, pmid + (size_t)(c * 3 + 2) * 65536, b_mid + (c * 3 + 2) * 256, lane, w);

    // Final 256 -> 3 + tanh, fp32 VALU.
    if (tid < 192) {
        const int p = tid & 63, o = tid >> 6;
        const bf16* hp = buf + p * LSTR;
        const float* wr = woutw + (c * 3 + o) * 256;
        float s = b_out[c * 3 + o];
        for (int k = 0; k < 256; k += 8) {
            const bf16x8 hv = *(const bf16x8*)(hp + k);
            const float4* wvp = (const float4*)(wr + k);
            const float4 w0 = wvp[0], w1 = wvp[1];
            s += (float)hv[0] * w0.x + (float)hv[1] * w0.y + (float)hv[2] * w0.z + (float)hv[3] * w0.w
               + (float)hv[4] * w1.x + (float)hv[5] * w1.y + (float)hv[6] * w1.z + (float)hv[7] * w1.w;
        }
        if (s0 + p < count) out[(size_t)sidx[p] * 3 + o] = tanhf(s);
    }
}

extern "C" void kernel_launch(void* const* d_in, const int* in_sizes, int n_in,
                              void* d_out, int out_size, void* d_ws, size_t ws_size,
                              hipStream_t stream) {
    const float* X     = (const float*)d_in[0];
    const int*   cid   = (const int*)d_in[1];
    const float* V_in  = (const float*)d_in[2];
    const float* g_in  = (const float*)d_in[3];
    const float* b_in  = (const float*)d_in[4];
    const float* V_mid = (const float*)d_in[5];
    const float* g_mid = (const float*)d_in[6];
    const float* b_mid = (const float*)d_in[7];
    const float* V_out = (const float*)d_in[8];
    const float* g_out = (const float*)d_in[9];
    const float* b_out = (const float*)d_in[10];
    float* out = (float*)d_out;

    char* ws = (char*)d_ws;
    int*   cursor = (int*)ws;                    // NCLUS entries, 128 B apart
    int*   order  = (int*)(ws + OFF_ORDER);
    bf16*  pin    = (bf16*)(ws + OFF_PIN);
    bf16*  pmid   = (bf16*)(ws + OFF_PMID);
    float* woutw  = (float*)(ws + OFF_WOUT);

    hipMemsetAsync(cursor, 0, NCLUS * CURPAD * sizeof(int), stream);
    setup_kernel<<<SCAT_BLKS + PREP_BLKS, 1024, 0, stream>>>(
        cid, cursor, order, V_in, g_in, V_mid, g_mid, V_out, g_out, pin, pmid, woutw);
    mlp_kernel<<<MLP_BLKS, 256, 0, stream>>>(X, b_in, b_mid, b_out, cursor, order,
                                             pin, pmid, woutw, out);
}